// Round 1
// baseline (640.781 us; speedup 1.0000x reference)
//
#include <hip/hip_runtime.h>
#include <stdint.h>
#include <stddef.h>

// AttentionLayer2D: B=4, N=64*64=4096, C=512, Cfg=64
// out = gamma * softmax(g @ f^T) @ h + x   (per batch), residual in fp32.

#define B_ 4
#define N_ 4096
#define C_ 512

typedef float f32x4 __attribute__((ext_vector_type(4)));
typedef short s16x8 __attribute__((ext_vector_type(8)));

__device__ __forceinline__ unsigned short f2bf(float f) {
  unsigned u = __builtin_bit_cast(unsigned, f);
  u += 0x7FFFu + ((u >> 16) & 1u);   // RNE
  return (unsigned short)(u >> 16);
}

// ---------- weight transpose + bf16 convert: wT[n][k], n in [0,640), k in [0,512)
// rows 0..63 = kernel_f^T, 64..127 = kernel_g^T, 128..639 = kernel_h^T
__global__ void wt_kernel(const float* __restrict__ kf, const float* __restrict__ kg,
                          const float* __restrict__ kh, unsigned short* __restrict__ wT) {
  const int n = blockIdx.x;
  const float* src; int stride;
  if (n < 64)       { src = kf + n;         stride = 64;  }
  else if (n < 128) { src = kg + (n - 64);  stride = 64;  }
  else              { src = kh + (n - 128); stride = 512; }
  for (int k = threadIdx.x; k < 512; k += blockDim.x)
    wT[(size_t)n * 512 + k] = f2bf(src[(size_t)k * stride]);
}

// ---------- fused projection GEMM: [16384 x 512] @ [512 x 640] -> f, g, hT (bf16)
// block: 256 thr = 4 waves, tile 64(M) x 64(N), wave w owns rows 16w..16w+15.
__global__ __launch_bounds__(256) void gemm_kernel(
    const float* __restrict__ x, const unsigned short* __restrict__ wT,
    const float* __restrict__ bf, const float* __restrict__ bg, const float* __restrict__ bh,
    unsigned short* __restrict__ fO, unsigned short* __restrict__ gO,
    unsigned short* __restrict__ hT)
{
  __shared__ unsigned short tile[64][64];
  const int tid = threadIdx.x;
  const int w = tid >> 6, l = tid & 63;
  const int l15 = l & 15, sub = l >> 4;
  const int mblock = blockIdx.x * 64;
  const int nblock = blockIdx.y * 64;

  const float* xrow = x + (size_t)(mblock + w * 16 + l15) * C_;

  f32x4 acc[4] = {{0,0,0,0},{0,0,0,0},{0,0,0,0},{0,0,0,0}};
  for (int kk = 0; kk < 512; kk += 32) {
    // A fragment: 8 consecutive k from this lane's row (m = lane&15, k = 8*(lane>>4)+i)
    f32x4 a0 = *(const f32x4*)(xrow + kk + 8 * sub);
    f32x4 a1 = *(const f32x4*)(xrow + kk + 8 * sub + 4);
    s16x8 af;
    af[0] = (short)f2bf(a0[0]); af[1] = (short)f2bf(a0[1]);
    af[2] = (short)f2bf(a0[2]); af[3] = (short)f2bf(a0[3]);
    af[4] = (short)f2bf(a1[0]); af[5] = (short)f2bf(a1[1]);
    af[6] = (short)f2bf(a1[2]); af[7] = (short)f2bf(a1[3]);
#pragma unroll
    for (int t = 0; t < 4; ++t) {
      const int n = nblock + 16 * t + l15;
      const s16x8 bfr = *(const s16x8*)(wT + (size_t)n * 512 + kk + 8 * sub);
      acc[t] = __builtin_amdgcn_mfma_f32_16x16x32_bf16(af, bfr, acc[t], 0, 0, 0);
    }
  }

  const bool isF = (nblock == 0), isG = (nblock == 64);
#pragma unroll
  for (int t = 0; t < 4; ++t) {
    const int n = nblock + 16 * t + l15;
    const float bv = (n < 64) ? bf[n] : (n < 128 ? bg[n - 64] : bh[n - 128]);
#pragma unroll
    for (int v = 0; v < 4; ++v) {
      const int r = w * 16 + 4 * sub + v;   // local row (q)
      const int c = 16 * t + l15;           // local col (n)
      const unsigned short bv16 = f2bf(acc[t][v] + bv);
      if (isF || isG) tile[r][c] = bv16;    // store [q][c]
      else            tile[c][r] = bv16;    // store [c][q] for transposed h
    }
  }
  __syncthreads();

  // coalesced 16B stores: 64 rows x 128B
  const int b = mblock >> 12;
  const int qb = mblock & 4095;
#pragma unroll
  for (int it = 0; it < 2; ++it) {
    const int u = tid + it * 256;
    const int rr = u >> 3, ch = u & 7;
    const s16x8 vdat = *(const s16x8*)&tile[rr][ch * 8];
    unsigned short* dst;
    if (isF)      dst = fO + (size_t)(mblock + rr) * 64 + ch * 8;
    else if (isG) dst = gO + (size_t)(mblock + rr) * 64 + ch * 8;
    else          dst = hT + ((size_t)b * 512 + (nblock - 128 + rr)) * 4096 + qb + ch * 8;
    *(s16x8*)dst = vdat;
  }
}

// ---------- flash attention: 1 wave per 16 q-rows, KBLK=32
__global__ __launch_bounds__(256) void attn_kernel(
    const unsigned short* __restrict__ fM, const unsigned short* __restrict__ gM,
    const unsigned short* __restrict__ hT, const float* __restrict__ x,
    const float* __restrict__ gamma, float* __restrict__ out)
{
  __shared__ unsigned short plds[4][16][32];   // per-wave P transpose staging
  const int tid = threadIdx.x;
  const int w = tid >> 6, l = tid & 63;
  const int l15 = l & 15, sub = l >> 4;
  const int wave = blockIdx.x * 4 + w;        // 0..1023
  const int b = wave >> 8;                    // 256 q-tiles per batch
  const int qbase = (wave & 255) * 16;

  // QK^T A-operand: g rows for this wave's 16 q-rows (hoisted; fixed all loop)
  const unsigned short* grow = gM + ((size_t)b * 4096 + qbase + l15) * 64;
  const s16x8 ga0 = *(const s16x8*)(grow + 8 * sub);        // c = 0..31
  const s16x8 ga1 = *(const s16x8*)(grow + 32 + 8 * sub);   // c = 32..63

  const unsigned short* fbase = fM + (size_t)b * 4096 * 64;
  const unsigned short* hbase = hT + (size_t)b * 512 * 4096 + (size_t)l15 * 4096;
  unsigned short* pw = &plds[w][0][0];

  float m[4], lsum[4];
#pragma unroll
  for (int v = 0; v < 4; ++v) { m[v] = -1e30f; lsum[v] = 0.f; }
  f32x4 o[32];
#pragma unroll
  for (int t = 0; t < 32; ++t) o[t] = (f32x4){0, 0, 0, 0};

  for (int jb = 0; jb < 128; ++jb) {
    const int j0 = jb * 32;
    // QK^T: s[16 q][32 j] as two 16x16 tiles
    const unsigned short* f0 = fbase + (size_t)(j0 + l15) * 64 + 8 * sub;
    const unsigned short* f1 = fbase + (size_t)(j0 + 16 + l15) * 64 + 8 * sub;
    const s16x8 fb00 = *(const s16x8*)(f0);
    const s16x8 fb01 = *(const s16x8*)(f0 + 32);
    const s16x8 fb10 = *(const s16x8*)(f1);
    const s16x8 fb11 = *(const s16x8*)(f1 + 32);
    f32x4 s0 = {0,0,0,0}, s1 = {0,0,0,0};
    s0 = __builtin_amdgcn_mfma_f32_16x16x32_bf16(ga0, fb00, s0, 0, 0, 0);
    s0 = __builtin_amdgcn_mfma_f32_16x16x32_bf16(ga1, fb01, s0, 0, 0, 0);
    s1 = __builtin_amdgcn_mfma_f32_16x16x32_bf16(ga0, fb10, s1, 0, 0, 0);
    s1 = __builtin_amdgcn_mfma_f32_16x16x32_bf16(ga1, fb11, s1, 0, 0, 0);

    // online softmax; C layout: col = lane&15, row = 4*(lane>>4)+v
    float scale[4], p0[4], p1[4];
#pragma unroll
    for (int v = 0; v < 4; ++v) {
      float mx = fmaxf(s0[v], s1[v]);
#pragma unroll
      for (int d = 1; d < 16; d <<= 1) mx = fmaxf(mx, __shfl_xor(mx, d));
      const float mnew = fmaxf(m[v], mx);
      scale[v] = __expf(m[v] - mnew);
      p0[v] = __expf(s0[v] - mnew);
      p1[v] = __expf(s1[v] - mnew);
      m[v] = mnew;
      float rs = p0[v] + p1[v];
#pragma unroll
      for (int d = 1; d < 16; d <<= 1) rs += __shfl_xor(rs, d);
      lsum[v] = lsum[v] * scale[v] + rs;
    }
    // rescale O
#pragma unroll
    for (int t = 0; t < 32; ++t) {
      o[t][0] *= scale[0]; o[t][1] *= scale[1];
      o[t][2] *= scale[2]; o[t][3] *= scale[3];
    }
    // transpose P (C-layout) -> A-fragment layout via wave-private LDS
#pragma unroll
    for (int v = 0; v < 4; ++v) {
      pw[(4 * sub + v) * 32 + l15]      = f2bf(p0[v]);
      pw[(4 * sub + v) * 32 + 16 + l15] = f2bf(p1[v]);
    }
    const s16x8 pa = *(const s16x8*)(pw + (size_t)l15 * 32 + 8 * sub);
    // PV: o[16 q][512] += P[16x32] @ H[32x512]; B-frag = contiguous 16B from hT row
#pragma unroll
    for (int t = 0; t < 32; ++t) {
      const s16x8 hb = *(const s16x8*)(hbase + (size_t)t * 16 * 4096 + j0 + 8 * sub);
      o[t] = __builtin_amdgcn_mfma_f32_16x16x32_bf16(pa, hb, o[t], 0, 0, 0);
    }
  }

  const float gam = gamma[0];
  float inv[4];
#pragma unroll
  for (int v = 0; v < 4; ++v) inv[v] = 1.0f / lsum[v];
  const float* xb = x + ((size_t)b * 4096 + qbase) * 512;
  float* ob = out + ((size_t)b * 4096 + qbase) * 512;
#pragma unroll
  for (int t = 0; t < 32; ++t) {
#pragma unroll
    for (int v = 0; v < 4; ++v) {
      const int r = 4 * sub + v;
      const int c = 16 * t + l15;
      const size_t idx = (size_t)r * 512 + c;
      ob[idx] = gam * (o[t][v] * inv[v]) + xb[idx];
    }
  }
}

extern "C" void kernel_launch(void* const* d_in, const int* in_sizes, int n_in,
                              void* d_out, int out_size, void* d_ws, size_t ws_size,
                              hipStream_t stream) {
  const float* x     = (const float*)d_in[0];
  const float* kf    = (const float*)d_in[1];
  const float* kg    = (const float*)d_in[2];
  const float* kh    = (const float*)d_in[3];
  const float* bf    = (const float*)d_in[4];
  const float* bg    = (const float*)d_in[5];
  const float* bh    = (const float*)d_in[6];
  const float* gamma = (const float*)d_in[7];
  float* out = (float*)d_out;

  // workspace layout (bytes): f [0,2M) g [2M,4M) hT [4M,20M) wT [20M,20.625M)
  char* ws = (char*)d_ws;
  unsigned short* fO = (unsigned short*)(ws);
  unsigned short* gO = (unsigned short*)(ws + (2u << 20));
  unsigned short* hT = (unsigned short*)(ws + (4u << 20));
  unsigned short* wT = (unsigned short*)(ws + (20u << 20));

  hipLaunchKernelGGL(wt_kernel,  dim3(640),     dim3(256), 0, stream, kf, kg, kh, wT);
  hipLaunchKernelGGL(gemm_kernel, dim3(256, 10), dim3(256), 0, stream,
                     x, wT, bf, bg, bh, fO, gO, hT);
  hipLaunchKernelGGL(attn_kernel, dim3(256),    dim3(256), 0, stream,
                     fO, gO, hT, x, gamma, out);
}